// Round 11
// baseline (263.767 us; speedup 1.0000x reference)
//
#include <hip/hip_runtime.h>

#define EPSV 1e-5f

typedef __attribute__((ext_vector_type(8))) short short8;
typedef __attribute__((ext_vector_type(4))) float f32x4;
typedef unsigned int uint;
typedef unsigned short ushort;

// ---------------- init: cnt=0, + graph segment starts (block 0) --------------
__global__ __launch_bounds__(256) void init_k(int* __restrict__ cnt,
                                              const int* __restrict__ batch,
                                              int* __restrict__ gstart,
                                              int nnodes, int ngraphs) {
    int i = blockIdx.x * 256 + threadIdx.x;
    if (i < nnodes) cnt[i] = 0;
    if (blockIdx.x == 0 && threadIdx.x <= ngraphs) {
        int g = threadIdx.x;
        int lo = 0, hi = nnodes;
        while (lo < hi) {
            int mid = (lo + hi) >> 1;
            if (batch[mid] < g) lo = mid + 1; else hi = mid;
        }
        gstart[g] = lo;
    }
}

__global__ __launch_bounds__(256) void degcount_k(const int* __restrict__ dst,
                                                  int* __restrict__ cnt,
                                                  int nedges) {
    int i = blockIdx.x * 256 + threadIdx.x;
    if (i < nedges) atomicAdd(&cnt[dst[i]], 1);
}

// ---------------- exclusive scan of cnt[] -> rowptr[] (+ dinv) ---------------
__global__ __launch_bounds__(256) void scan1_k(const int* __restrict__ cnt,
                                               int* __restrict__ rowptr,
                                               int* __restrict__ bsum,
                                               float* __restrict__ dinv, int n) {
    __shared__ int sh[256];
    const int tx = threadIdx.x;
    const int base = blockIdx.x * 1024;
    int v[4];
    int s = 0;
#pragma unroll
    for (int j = 0; j < 4; j++) {
        int idx = base + tx * 4 + j;
        v[j] = (idx < n) ? cnt[idx] : 0;
        if (idx < n) dinv[idx] = rsqrtf(1.0f + (float)v[j]);
        s += v[j];
    }
    sh[tx] = s;
    __syncthreads();
#pragma unroll
    for (int off = 1; off < 256; off <<= 1) {
        int t = (tx >= off) ? sh[tx - off] : 0;
        __syncthreads();
        sh[tx] += t;
        __syncthreads();
    }
    int run = sh[tx] - s;
#pragma unroll
    for (int j = 0; j < 4; j++) {
        int idx = base + tx * 4 + j;
        if (idx < n) rowptr[idx] = run;
        run += v[j];
    }
    if (tx == 255) bsum[blockIdx.x] = sh[255];
}

__global__ __launch_bounds__(64) void scan2_k(int* __restrict__ bsum, int nb) {
    __shared__ int sh[64];
    const int tx = threadIdx.x;
    int v = (tx < nb) ? bsum[tx] : 0;
    sh[tx] = v;
    __syncthreads();
#pragma unroll
    for (int off = 1; off < 64; off <<= 1) {
        int t = (tx >= off) ? sh[tx - off] : 0;
        __syncthreads();
        sh[tx] += t;
        __syncthreads();
    }
    if (tx < nb) bsum[tx] = sh[tx] - v;
}

__global__ __launch_bounds__(256) void scan3_k(int* __restrict__ rowptr,
                                               int* __restrict__ cur,
                                               const int* __restrict__ bsum,
                                               int n, int nedges) {
    const int tx = threadIdx.x;
    const int base = blockIdx.x * 1024;
    int off = bsum[blockIdx.x];
#pragma unroll
    for (int j = 0; j < 4; j++) {
        int idx = base + tx * 4 + j;
        if (idx < n) {
            int r = rowptr[idx] + off;
            rowptr[idx] = r;
            cur[idx] = r;
        }
    }
    if (blockIdx.x == 0 && tx == 0) rowptr[n] = nedges;
}

__global__ __launch_bounds__(256) void fill_k(const int* __restrict__ src,
                                              const int* __restrict__ dst,
                                              int* __restrict__ cur,
                                              int* __restrict__ esrc, int nedges) {
    int i = blockIdx.x * 256 + threadIdx.x;
    if (i >= nedges) return;
    int pos = atomicAdd(&cur[dst[i]], 1);
    esrc[pos] = src[i];
}

// ---------------- W prep: transpose + bf16 RNE, both layers ------------------
__global__ __launch_bounds__(256) void wprep_k(const float* __restrict__ W1,
                                               const float* __restrict__ W2,
                                               ushort* __restrict__ wt1,
                                               ushort* __restrict__ wt2) {
    int i = blockIdx.x * 256 + threadIdx.x;
    if (i < 512 * 128) {
        int k = i >> 7, c = i & 127;
        unsigned u = __builtin_bit_cast(unsigned, W1[i]);
        wt1[c * 512 + k] = (ushort)((u + 0x7fffu + ((u >> 16) & 1u)) >> 16);
    } else if (i < 512 * 128 + 128 * 128) {
        int j = i - 512 * 128;
        int k = j >> 7, c = j & 127;
        unsigned u = __builtin_bit_cast(unsigned, W2[j]);
        wt2[c * 128 + k] = (ushort)((u + 0x7fffu + ((u >> 16) & 1u)) >> 16);
    }
}

// ---------------- MFMA GEMM: H = X @ W, + fused hb = bf16(H*dinv) -----------
// A split-bf16 (ah+al, exact), B pure bf16-RNE.
// 256 thr = 4 waves; BM=32: wave = 16 rows (wrow=wu>>1) x 64 cols (wcol=wu&1).
// B in 2-buffer LDS (2 x 16 KB = one 64-k slice pair each):
//   [c 128][slot 8 x 16B], slot s = sub*4 + kgrp, stored at s ^ (c&7).
// Per iter: [vmcnt(N); s_barrier; STAGE(i+1); A-load(i+2); compute buf[i&1]].
//   N: i==0 -> 8 (S0 + A0[4]+A1[4] issued after), mid -> 4 (A(i+1) newer
//   than S(i)), last -> 0.  A prefetched 2 iters deep (3 register sets).
template <int K>
__global__ __launch_bounds__(256) void gemm_mfma_k(const float* __restrict__ X,
                                                   const ushort* __restrict__ wT,
                                                   const float* __restrict__ dinv,
                                                   float* __restrict__ H,
                                                   ushort* __restrict__ hb16,
                                                   int nrows) {
    __shared__ ushort bsm[2][8192];   // 2 x 16 KB

    const int tx = threadIdx.x;
    const int wu = __builtin_amdgcn_readfirstlane(tx >> 6);
    const int l = tx & 63;
    const int lrow = l & 15;
    const int kgrp = l >> 4;
    const int wrow = wu >> 1;         // 0..1: 16-row stripe
    const int wcol = wu & 1;          // 0..1: 64-col half
    const int row0 = blockIdx.x * 32 + wrow * 16;

    // staging source pointers (per-lane, pre-swizzled): phys slot = s ^ (c&7)
    const ushort* sp[4];
#pragma unroll
    for (int q = 0; q < 4; q++) {
        int chunk = (wu * 4 + q) * 64 + l;       // 16B-chunk id in slice pair
        int c = chunk >> 3;
        int s = (chunk & 7) ^ (c & 7);           // unswizzled slot -> k-off s*8
        sp[q] = wT + (size_t)c * K + s * 8;
    }

    int arow = row0 + lrow;
    if (arow >= nrows) arow = nrows - 1;         // clamp (store guarded)
    const float* xrow = X + (size_t)arow * K + kgrp * 8;

    f32x4 acc[4];
#pragma unroll
    for (int g = 0; g < 4; g++) acc[g] = (f32x4){0.f, 0.f, 0.f, 0.f};

    auto STAGE = [&](int buf, int k0) {
#pragma unroll
        for (int q = 0; q < 4; q++) {
            const ushort* src = sp[q] + k0;
            ushort* dst = &bsm[buf][(wu * 4 + q) * 512];   // +lane*16B by HW
            __builtin_amdgcn_global_load_lds(
                (const __attribute__((address_space(1))) unsigned int*)(const void*)src,
                (__attribute__((address_space(3))) unsigned int*)(void*)dst,
                16, 0, 0);
        }
    };

    constexpr int NIT = K / 64;

    // prologue: stage pair 0; A for iters 0 and 1 (order pinned by mem-asm)
    STAGE(0, 0);
    asm volatile("" ::: "memory");
    f32x4 c0 = *reinterpret_cast<const f32x4*>(xrow);
    f32x4 c1 = *reinterpret_cast<const f32x4*>(xrow + 4);
    f32x4 c2 = *reinterpret_cast<const f32x4*>(xrow + 32);
    f32x4 c3 = *reinterpret_cast<const f32x4*>(xrow + 36);
    f32x4 d0 = c0, d1 = c1, d2 = c2, d3 = c3;
    if (NIT > 1) {
        d0 = *reinterpret_cast<const f32x4*>(xrow + 64);
        d1 = *reinterpret_cast<const f32x4*>(xrow + 68);
        d2 = *reinterpret_cast<const f32x4*>(xrow + 96);
        d3 = *reinterpret_cast<const f32x4*>(xrow + 100);
    }

#pragma unroll
    for (int i = 0; i < NIT; i++) {
        if (i == 0 && NIT > 1)   asm volatile("s_waitcnt vmcnt(8)" ::: "memory");
        else if (i + 1 < NIT)    asm volatile("s_waitcnt vmcnt(4)" ::: "memory");
        else                     asm volatile("s_waitcnt vmcnt(0)" ::: "memory");
        __builtin_amdgcn_s_barrier();
        __builtin_amdgcn_sched_barrier(0);

        // stage next slice pair into the buffer whose readers just passed
        if (i + 1 < NIT) STAGE((i + 1) & 1, (i + 1) * 64);
        asm volatile("" ::: "memory");

        // A prefetch: iter i+2
        f32x4 e0 = d0, e1 = d1, e2 = d2, e3 = d3;
        if (i + 2 < NIT) {
            const float* nx = xrow + (i + 2) * 64;
            e0 = *reinterpret_cast<const f32x4*>(nx);
            e1 = *reinterpret_cast<const f32x4*>(nx + 4);
            e2 = *reinterpret_cast<const f32x4*>(nx + 32);
            e3 = *reinterpret_cast<const f32x4*>(nx + 36);
        }

        const ushort* b = bsm[i & 1];
#pragma unroll
        for (int sub = 0; sub < 2; sub++) {
            // A fragment: 8 contiguous f32 -> bf16 hi/lo (exact split)
            short8 ah, al;
#pragma unroll
            for (int j = 0; j < 8; j++) {
                float f = (sub == 0) ? ((j < 4) ? c0[j] : c1[j - 4])
                                     : ((j < 4) ? c2[j] : c3[j - 4]);
                unsigned u = __builtin_bit_cast(unsigned, f);
                ah[j] = (short)(u >> 16);
                float hif = __builtin_bit_cast(float, u & 0xffff0000u);
                float lof = f - hif;
                al[j] = (short)(__builtin_bit_cast(unsigned, lof) >> 16);
            }
#pragma unroll
            for (int g = 0; g < 4; g++) {
                int cc = (wcol * 4 + g) * 16 + lrow;
                int phys = (sub * 4 + kgrp) ^ (cc & 7);
                short8 bb = *reinterpret_cast<const short8*>(&b[cc * 64 + phys * 8]);
                acc[g] = __builtin_amdgcn_mfma_f32_16x16x32_bf16(ah, bb, acc[g], 0, 0, 0);
                acc[g] = __builtin_amdgcn_mfma_f32_16x16x32_bf16(al, bb, acc[g], 0, 0, 0);
            }
        }

        c0 = d0; c1 = d1; c2 = d2; c3 = d3;
        d0 = e0; d1 = e1; d2 = e2; d3 = e3;
    }

    // C: row = row0 + kgrp*4 + r, col = wcol*64 + g*16 + lrow (m89 mapping)
#pragma unroll
    for (int r = 0; r < 4; r++) {
        int row = row0 + kgrp * 4 + r;
        if (row < nrows) {
            float dn = dinv[row];
            float* hrow = H + (size_t)row * 128 + wcol * 64 + lrow;
            ushort* hbrow = hb16 + (size_t)row * 128 + wcol * 64 + lrow;
#pragma unroll
            for (int g = 0; g < 4; g++) {
                float v = acc[g][r];
                hrow[g * 16] = v;
                unsigned u = __builtin_bit_cast(unsigned, v * dn);
                hbrow[g * 16] = (ushort)((u + 0x7fffu + ((u >> 16) & 1u)) >> 16);
            }
        }
    }
}

// ------ fused aggregate: out[d] = dinv[d]*(h[d]*dinv[d] + sum hb[src]) -------
// then bias + BN(eval) + ReLU.  One 64-lane wave per node, 4 B/lane gathers.
__global__ __launch_bounds__(256) void agg_k(const float* __restrict__ H,
                                             const uint* __restrict__ hb,
                                             const int* __restrict__ rowptr,
                                             const int* __restrict__ esrc,
                                             const float* __restrict__ dinv,
                                             const float* __restrict__ bias,
                                             const float* __restrict__ gamma,
                                             const float* __restrict__ beta,
                                             const float* __restrict__ rm,
                                             const float* __restrict__ rv,
                                             float* __restrict__ OUT,
                                             int nnodes) {
    int node = blockIdx.x * 4 + (threadIdx.x >> 6);
    if (node >= nnodes) return;
    node = __builtin_amdgcn_readfirstlane(node);
    const int l = threadIdx.x & 63;
    const int c = l * 2;
    const float dn = dinv[node];
    const int beg = rowptr[node], end = rowptr[node + 1];

    float2 hv = *reinterpret_cast<const float2*>(H + (size_t)node * 128 + c);
    float ax0 = hv.x * dn, ay0 = hv.y * dn;
    float ax1 = 0.f, ay1 = 0.f, ax2 = 0.f, ay2 = 0.f, ax3 = 0.f, ay3 = 0.f;
    const uint* hbl = hb + l;

    int j = beg;
    for (; j + 3 < end; j += 4) {
        int s0 = esrc[j], s1 = esrc[j + 1], s2 = esrc[j + 2], s3 = esrc[j + 3];
        uint u0 = hbl[(size_t)s0 * 64];
        uint u1 = hbl[(size_t)s1 * 64];
        uint u2 = hbl[(size_t)s2 * 64];
        uint u3 = hbl[(size_t)s3 * 64];
        ax0 += __builtin_bit_cast(float, u0 << 16);
        ay0 += __builtin_bit_cast(float, u0 & 0xffff0000u);
        ax1 += __builtin_bit_cast(float, u1 << 16);
        ay1 += __builtin_bit_cast(float, u1 & 0xffff0000u);
        ax2 += __builtin_bit_cast(float, u2 << 16);
        ay2 += __builtin_bit_cast(float, u2 & 0xffff0000u);
        ax3 += __builtin_bit_cast(float, u3 << 16);
        ay3 += __builtin_bit_cast(float, u3 & 0xffff0000u);
    }
    for (; j < end; j++) {
        uint u0 = hbl[(size_t)esrc[j] * 64];
        ax0 += __builtin_bit_cast(float, u0 << 16);
        ay0 += __builtin_bit_cast(float, u0 & 0xffff0000u);
    }
    float accx = (ax0 + ax1) + (ax2 + ax3);
    float accy = (ay0 + ay1) + (ay2 + ay3);

    float v0 = accx * dn + bias[c];
    float v1 = accy * dn + bias[c + 1];
    v0 = (v0 - rm[c])     * rsqrtf(rv[c] + EPSV)     * gamma[c]     + beta[c];
    v1 = (v1 - rm[c + 1]) * rsqrtf(rv[c + 1] + EPSV) * gamma[c + 1] + beta[c + 1];
    v0 = fmaxf(v0, 0.0f);
    v1 = fmaxf(v1, 0.0f);

    *reinterpret_cast<float2*>(OUT + (size_t)node * 128 + c) = make_float2(v0, v1);
}

// ---------------- mean pool, stage 1: per-(graph, chunk) partial sums --------
__global__ __launch_bounds__(256) void pool1_k(const float* __restrict__ V,
                                               const int* __restrict__ gstart,
                                               float* __restrict__ partial) {
    __shared__ float sh[256];
    const int g = blockIdx.x >> 5;
    const int p = blockIdx.x & 31;
    const int tx = threadIdx.x;
    const int ch = tx & 127;
    const int sub = tx >> 7;
    const int beg = gstart[g], end = gstart[g + 1];
    const int chunk = (end - beg + 31) >> 5;
    const int s = beg + p * chunk;
    const int e = min(s + chunk, end);
    float acc = 0.0f;
    for (int i = s + sub; i < e; i += 2)
        acc += V[(size_t)i * 128 + ch];
    sh[tx] = acc;
    __syncthreads();
    if (tx < 128)
        partial[(size_t)blockIdx.x * 128 + tx] = sh[tx] + sh[tx + 128];
}

// ---------------- mean pool, stage 2 -----------------------------------------
__global__ __launch_bounds__(128) void pool2_k(const float* __restrict__ partial,
                                               const int* __restrict__ gstart,
                                               float* __restrict__ pooled) {
    const int g = blockIdx.x;
    const int ch = threadIdx.x;
    float s = 0.0f;
#pragma unroll
    for (int p = 0; p < 32; p++)
        s += partial[(size_t)((g << 5) + p) * 128 + ch];
    float cnt = fmaxf((float)(gstart[g + 1] - gstart[g]), 1.0f);
    pooled[g * 128 + ch] = s / cnt;
}

// ---------------- final: out[g][o] = pooled[g] @ Wl + bl ---------------------
__global__ __launch_bounds__(128) void final_k(const float* __restrict__ pooled,
                                               const float* __restrict__ Wl,
                                               const float* __restrict__ bl,
                                               float* __restrict__ out) {
    int tx = threadIdx.x;
    int g = tx >> 1, o = tx & 1;
    float s = 0.0f;
#pragma unroll 8
    for (int c = 0; c < 128; c++) s += pooled[g * 128 + c] * Wl[c * 2 + o];
    out[tx] = s + bl[o];
}

extern "C" void kernel_launch(void* const* d_in, const int* in_sizes, int n_in,
                              void* d_out, int out_size, void* d_ws, size_t ws_size,
                              hipStream_t stream) {
    const float* x      = (const float*)d_in[0];
    const int*   ei     = (const int*)d_in[1];
    const int*   batch  = (const int*)d_in[2];
    const float* W1     = (const float*)d_in[3];
    const float* b1     = (const float*)d_in[4];
    const float* gamma1 = (const float*)d_in[5];
    const float* beta1  = (const float*)d_in[6];
    const float* rm1    = (const float*)d_in[7];
    const float* rv1    = (const float*)d_in[8];
    const float* W2     = (const float*)d_in[9];
    const float* b2     = (const float*)d_in[10];
    const float* gamma2 = (const float*)d_in[11];
    const float* beta2  = (const float*)d_in[12];
    const float* rm2    = (const float*)d_in[13];
    const float* rv2    = (const float*)d_in[14];
    const float* Wl     = (const float*)d_in[15];
    const float* bl     = (const float*)d_in[16];
    float* out = (float*)d_out;

    const int nnodes  = in_sizes[2];
    const int nedges  = in_sizes[1] / 2;
    const int ngraphs = 64;
    const int* srcp = ei;
    const int* dstp = ei + nedges;

    float* wsA     = (float*)d_ws;                       // [nnodes*128]
    float* wsB     = wsA + (size_t)nnodes * 128;         // [nnodes*128]
    float* dinv    = wsB + (size_t)nnodes * 128;         // [nnodes]
    float* pooled  = dinv + nnodes;                      // [64*128]
    float* partial = pooled + 64 * 128;                  // [64*32*128]
    int*   cnt     = (int*)(partial + 64 * 32 * 128);    // [nnodes]
    int*   rowptr  = cnt + nnodes;                       // [nnodes+1]
    int*   cur     = rowptr + nnodes + 1;                // [nnodes]
    int*   bsum    = cur + nnodes;                       // [64]
    int*   gstart  = bsum + 64;                          // [65]
    int*   esrc    = gstart + 65;                        // [nedges]
    uintptr_t wp   = ((uintptr_t)(esrc + nedges) + 15) & ~(uintptr_t)15;
    ushort* wt1  = (ushort*)wp;                          // [128*512]
    ushort* wt2  = wt1 + 512 * 128;                      // [128*128]
    ushort* hb16 = wt2 + 128 * 128;                      // [nnodes*128] bf16
    uint*   hb   = (uint*)hb16;                          // same buffer, uint view

    dim3 blk(256);
    const int gNodes = (nnodes + 255) / 256;
    const int gEdges = (nedges + 255) / 256;
    const int gGemm  = (nnodes + 31) / 32;
    const int gAgg   = (nnodes + 3) / 4;
    const int nScanB = (nnodes + 1023) / 1024;

    // ---- graph preprocessing (CSR by dst + graph segments + W prep) ----
    init_k<<<gNodes, blk, 0, stream>>>(cnt, batch, gstart, nnodes, ngraphs);
    wprep_k<<<(512 * 128 + 128 * 128 + 255) / 256, blk, 0, stream>>>(W1, W2, wt1, wt2);
    degcount_k<<<gEdges, blk, 0, stream>>>(dstp, cnt, nedges);
    scan1_k<<<nScanB, blk, 0, stream>>>(cnt, rowptr, bsum, dinv, nnodes);
    scan2_k<<<1, 64, 0, stream>>>(bsum, nScanB);
    scan3_k<<<nScanB, blk, 0, stream>>>(rowptr, cur, bsum, nnodes, nedges);
    fill_k<<<gEdges, blk, 0, stream>>>(srcp, dstp, cur, esrc, nedges);

    // ---- layer 1: MFMA GEMM (+hb) + fused aggregate/BN/ReLU ----
    gemm_mfma_k<512><<<gGemm, blk, 0, stream>>>(x, wt1, dinv, wsA, hb16, nnodes);
    agg_k<<<gAgg, blk, 0, stream>>>(wsA, hb, rowptr, esrc, dinv, b1, gamma1, beta1,
                                    rm1, rv1, wsB, nnodes);

    // ---- layer 2: MFMA GEMM (+hb) + fused aggregate/BN/ReLU ----
    gemm_mfma_k<128><<<gGemm, blk, 0, stream>>>(wsB, wt2, dinv, wsA, hb16, nnodes);
    agg_k<<<gAgg, blk, 0, stream>>>(wsA, hb, rowptr, esrc, dinv, b2, gamma2, beta2,
                                    rm2, rv2, wsB, nnodes);

    // ---- readout ----
    pool1_k<<<ngraphs * 32, blk, 0, stream>>>(wsB, gstart, partial);
    pool2_k<<<ngraphs, 128, 0, stream>>>(partial, gstart, pooled);
    final_k<<<1, 128, 0, stream>>>(pooled, Wl, bl, out);
}